// Round 3
// baseline (481.473 us; speedup 1.0000x reference)
//
#include <hip/hip_runtime.h>
#include <math.h>

#define HDIM 256

typedef float floatx4 __attribute__((ext_vector_type(4)));
typedef __bf16 bf16x8 __attribute__((ext_vector_type(8)));
typedef unsigned short ushortx4 __attribute__((ext_vector_type(4)));
typedef unsigned short ushort_t;

#define AS1C(p) ((const __attribute__((address_space(1))) void*)(p))
#define AS3(p)  ((__attribute__((address_space(3))) void*)(p))

__device__ inline unsigned short bf16_rn(float f) {
  unsigned u = __float_as_uint(f);
  return (unsigned short)((u + 0x7FFFu + ((u >> 16) & 1u)) >> 16);
}

__device__ inline void split_f32(float f, unsigned short& h, unsigned short& l) {
  unsigned short hb = bf16_rn(f);
  float hf = __uint_as_float(((unsigned)hb) << 16);
  h = hb;
  l = bf16_rn(f - hf);
}

__device__ inline float bf2f(unsigned short b) {
  return __uint_as_float(((unsigned)b) << 16);
}

// ---------------- weight prep: W[K][256] fp32 -> Wt_hi/Wt_lo [256][K] bf16 ----------------

__global__ __launch_bounds__(256)
void prep_w_kernel(const float* __restrict__ W, unsigned short* __restrict__ WH,
                   unsigned short* __restrict__ WL, int kshift) {
  int idx = blockIdx.x * 256 + threadIdx.x;
  int K = 1 << kshift;
  if (idx >= (K << 8)) return;
  int c = idx >> kshift;
  int k = idx & (K - 1);
  float f = W[(size_t)k * HDIM + c];
  unsigned short h, l;
  split_f32(f, h, l);
  WH[idx] = h;
  WL[idx] = l;
}

// ---------------- CSR build ----------------

__global__ __launch_bounds__(256)
void deg_count_kernel(const int* __restrict__ ei, int* __restrict__ deg, int E) {
  int e = blockIdx.x * 256 + threadIdx.x;
  if (e < E) atomicAdd(&deg[ei[E + e]], 1);
}

__global__ __launch_bounds__(256)
void dinv_kernel(const int* __restrict__ deg, float* __restrict__ dinv, int n) {
  int i = blockIdx.x * 256 + threadIdx.x;
  if (i < n) dinv[i] = 1.0f / sqrtf((float)deg[i] + 1.0f);
}

__global__ __launch_bounds__(256)
void block_sum_kernel(const int* __restrict__ deg, int* __restrict__ bsum, int n) {
  __shared__ int sm[256];
  int t = threadIdx.x;
  int idx = blockIdx.x * 256 + t;
  sm[t] = (idx < n) ? deg[idx] : 0;
  __syncthreads();
  for (int off = 128; off > 0; off >>= 1) {
    if (t < off) sm[t] += sm[t + off];
    __syncthreads();
  }
  if (t == 0) bsum[blockIdx.x] = sm[0];
}

__global__ __launch_bounds__(256)
void scan_bsums_kernel(const int* __restrict__ bsum, int* __restrict__ boff,
                       int* __restrict__ rowptr, int nb, int n) {
  __shared__ int sm[256];
  int t = threadIdx.x;
  int v = (t < nb) ? bsum[t] : 0;
  sm[t] = v;
  __syncthreads();
  for (int off = 1; off < 256; off <<= 1) {
    int a = (t >= off) ? sm[t - off] : 0;
    __syncthreads();
    sm[t] += a;
    __syncthreads();
  }
  if (t < nb) boff[t] = sm[t] - v;
  if (t == 255) rowptr[n] = sm[255];
}

__global__ __launch_bounds__(256)
void scan_final_kernel(const int* __restrict__ deg, const int* __restrict__ boff,
                       int* __restrict__ rowptr, int* __restrict__ cursor, int n) {
  __shared__ int sm[256];
  int t = threadIdx.x;
  int idx = blockIdx.x * 256 + t;
  int v = (idx < n) ? deg[idx] : 0;
  sm[t] = v;
  __syncthreads();
  for (int off = 1; off < 256; off <<= 1) {
    int a = (t >= off) ? sm[t - off] : 0;
    __syncthreads();
    sm[t] += a;
    __syncthreads();
  }
  int excl = sm[t] - v + boff[blockIdx.x];
  if (idx < n) { rowptr[idx] = excl; cursor[idx] = excl; }
}

__global__ __launch_bounds__(256)
void fill_csr_kernel(const int* __restrict__ ei, int* __restrict__ cursor,
                     int* __restrict__ col, int E) {
  int e = blockIdx.x * 256 + threadIdx.x;
  if (e < E) {
    int s = ei[e];
    int d = ei[E + e];
    int p = atomicAdd(&cursor[d], 1);
    col[p] = s;
  }
}

// ---------------- GEMM 1: A fp32 (split in-kernel), tile 128x128, writes planes ----------------

template<bool BIAS, bool RELU>
__global__ __launch_bounds__(256, 3)
void mfma_gemm_splitA(const float* __restrict__ A,
                      const unsigned short* __restrict__ WH,
                      const unsigned short* __restrict__ WL,
                      const float* __restrict__ bias,
                      unsigned short* __restrict__ CH, unsigned short* __restrict__ CL,
                      int M, int K) {
  __shared__ __align__(16) unsigned short AsH[128 * 40];
  __shared__ __align__(16) unsigned short AsL[128 * 40];
  __shared__ __align__(16) unsigned short BsH[4096];
  __shared__ __align__(16) unsigned short BsL[4096];

  const int tid = threadIdx.x;
  const int w = tid >> 6;
  const int l = tid & 63;
  const int l15 = l & 15;
  const int quad = l >> 4;
  const int wm = w & 1;
  const int wn = w >> 1;
  const int bm = blockIdx.y * 128;
  const int bn = blockIdx.x * 128;

  floatx4 acc[4][4];
#pragma unroll
  for (int i = 0; i < 4; ++i)
#pragma unroll
    for (int j = 0; j < 4; ++j) acc[i][j] = (floatx4){0.f, 0.f, 0.f, 0.f};

  for (int k0 = 0; k0 < K; k0 += 32) {
    float4 av[4];
#pragma unroll
    for (int i = 0; i < 4; ++i) {
      int chunk = i * 256 + tid;
      int row = chunk >> 3;
      int kc4 = chunk & 7;
      int grow = bm + row;
      if (grow > M - 1) grow = M - 1;
      av[i] = *(const float4*)(A + (size_t)grow * K + k0 + kc4 * 4);
    }

    __syncthreads();

#pragma unroll
    for (int j = 0; j < 2; ++j) {
      int L = j * 256 + w * 64 + l;
      int kc = L >> 7;
      int colL = L & 127;
      const unsigned short* gH = WH + (size_t)(bn + colL) * K + k0 + kc * 8;
      const unsigned short* gL = WL + (size_t)(bn + colL) * K + k0 + kc * 8;
      __builtin_amdgcn_global_load_lds(AS1C(gH), AS3(&BsH[(j * 256 + w * 64) * 8]), 16, 0, 0);
      __builtin_amdgcn_global_load_lds(AS1C(gL), AS3(&BsL[(j * 256 + w * 64) * 8]), 16, 0, 0);
    }

#pragma unroll
    for (int i = 0; i < 4; ++i) {
      int chunk = i * 256 + tid;
      int row = chunk >> 3;
      int kc4 = chunk & 7;
      unsigned short h0, h1, h2, h3, l0, l1, l2, l3;
      split_f32(av[i].x, h0, l0);
      split_f32(av[i].y, h1, l1);
      split_f32(av[i].z, h2, l2);
      split_f32(av[i].w, h3, l3);
      ushortx4 hv = {h0, h1, h2, h3};
      ushortx4 lv = {l0, l1, l2, l3};
      *(ushortx4*)&AsH[row * 40 + kc4 * 4] = hv;
      *(ushortx4*)&AsL[row * 40 + kc4 * 4] = lv;
    }

    __syncthreads();

    bf16x8 aH[4], aL[4];
#pragma unroll
    for (int fi = 0; fi < 4; ++fi) {
      int row = wm * 64 + fi * 16 + l15;
      aH[fi] = *(const bf16x8*)&AsH[row * 40 + quad * 8];
      aL[fi] = *(const bf16x8*)&AsL[row * 40 + quad * 8];
    }
#pragma unroll
    for (int fj = 0; fj < 4; ++fj) {
      int colL = wn * 64 + fj * 16 + l15;
      int cidx = quad * 128 + colL;
      bf16x8 bh = *(const bf16x8*)&BsH[cidx * 8];
      bf16x8 bl = *(const bf16x8*)&BsL[cidx * 8];
#pragma unroll
      for (int fi = 0; fi < 4; ++fi) {
        floatx4 t = acc[fi][fj];
        t = __builtin_amdgcn_mfma_f32_16x16x32_bf16(aH[fi], bl, t, 0, 0, 0);
        t = __builtin_amdgcn_mfma_f32_16x16x32_bf16(aL[fi], bh, t, 0, 0, 0);
        t = __builtin_amdgcn_mfma_f32_16x16x32_bf16(aH[fi], bh, t, 0, 0, 0);
        acc[fi][fj] = t;
      }
    }
  }

  float bcol[4];
#pragma unroll
  for (int fj = 0; fj < 4; ++fj)
    bcol[fj] = BIAS ? bias[bn + wn * 64 + fj * 16 + l15] : 0.f;

#pragma unroll
  for (int fi = 0; fi < 4; ++fi) {
    int rb = bm + wm * 64 + fi * 16 + quad * 4;
#pragma unroll
    for (int r = 0; r < 4; ++r) {
      int row = rb + r;
      if (row < M) {
        size_t base = (size_t)row * HDIM + bn + wn * 64 + l15;
#pragma unroll
        for (int fj = 0; fj < 4; ++fj) {
          float v = acc[fi][fj][r] + bcol[fj];
          if (RELU) v = fmaxf(v, 0.f);
          unsigned short h, lo;
          split_f32(v, h, lo);
          CH[base + fj * 16] = h;
          CL[base + fj * 16] = lo;
        }
      }
    }
  }
}

// ---------------- GEMM 2: A = hi/lo planes via global_load_lds, tile 128x256 ----------------
// A-plane row stride 256. XOR swizzle on k-chunks keeps global 64B coalescing and <=2-way LDS conflicts.

template<bool BIAS, bool RELU, bool SPLIT_OUT>
__global__ __launch_bounds__(256, 2)
void mfma_gemm2(const unsigned short* __restrict__ AH, const unsigned short* __restrict__ AL,
                const unsigned short* __restrict__ WH, const unsigned short* __restrict__ WL,
                const float* __restrict__ bias,
                float* __restrict__ C, unsigned short* __restrict__ CH,
                unsigned short* __restrict__ CL, int M) {
  __shared__ __align__(16) unsigned short AsH[128 * 32];  // chunk L: row=L>>2, kc swizzled
  __shared__ __align__(16) unsigned short AsL[128 * 32];
  __shared__ __align__(16) unsigned short BsH[32 * 256];  // chunk: kc*256+col
  __shared__ __align__(16) unsigned short BsL[32 * 256];

  const int tid = threadIdx.x;
  const int w = tid >> 6;
  const int l = tid & 63;
  const int l15 = l & 15;
  const int quad = l >> 4;
  const int wm = w & 1;   // row stripe of 64
  const int wn = w >> 1;  // col stripe of 128
  const int bm = blockIdx.x * 128;

  floatx4 acc[4][8];
#pragma unroll
  for (int i = 0; i < 4; ++i)
#pragma unroll
    for (int j = 0; j < 8; ++j) acc[i][j] = (floatx4){0.f, 0.f, 0.f, 0.f};

  for (int k0 = 0; k0 < HDIM; k0 += 32) {
    __syncthreads();  // prior tile's LDS reads done

    // A: 512 chunks/plane, 2 per thread per plane
#pragma unroll
    for (int i = 0; i < 2; ++i) {
      int L = i * 256 + tid;
      int row = L >> 2;
      int kcL = L & 3;
      int kc = kcL ^ (row & 3) ^ ((row >> 2) & 3);
      int grow = bm + row;
      if (grow > M - 1) grow = M - 1;
      const unsigned short* gH = AH + (size_t)grow * HDIM + k0 + kc * 8;
      const unsigned short* gL = AL + (size_t)grow * HDIM + k0 + kc * 8;
      __builtin_amdgcn_global_load_lds(AS1C(gH), AS3(&AsH[(i * 256 + w * 64) * 8]), 16, 0, 0);
      __builtin_amdgcn_global_load_lds(AS1C(gL), AS3(&AsL[(i * 256 + w * 64) * 8]), 16, 0, 0);
    }
    // B: 1024 chunks/plane, 4 per thread per plane
#pragma unroll
    for (int j = 0; j < 4; ++j) {
      int L = j * 256 + tid;
      int kc = L >> 8;
      int colL = L & 255;
      const unsigned short* gH = WH + (size_t)colL * HDIM + k0 + kc * 8;
      const unsigned short* gL = WL + (size_t)colL * HDIM + k0 + kc * 8;
      __builtin_amdgcn_global_load_lds(AS1C(gH), AS3(&BsH[(j * 256 + w * 64) * 8]), 16, 0, 0);
      __builtin_amdgcn_global_load_lds(AS1C(gL), AS3(&BsL[(j * 256 + w * 64) * 8]), 16, 0, 0);
    }

    __syncthreads();  // vmcnt drained

    bf16x8 aH[4], aL[4];
#pragma unroll
    for (int fi = 0; fi < 4; ++fi) {
      int r = wm * 64 + fi * 16 + l15;
      int sw = quad ^ (r & 3) ^ ((r >> 2) & 3);
      aH[fi] = *(const bf16x8*)&AsH[(r * 4 + sw) * 8];
      aL[fi] = *(const bf16x8*)&AsL[(r * 4 + sw) * 8];
    }
#pragma unroll
    for (int fj = 0; fj < 8; ++fj) {
      int colL = wn * 128 + fj * 16 + l15;
      int cidx = quad * 256 + colL;
      bf16x8 bh = *(const bf16x8*)&BsH[cidx * 8];
      bf16x8 bl = *(const bf16x8*)&BsL[cidx * 8];
#pragma unroll
      for (int fi = 0; fi < 4; ++fi) {
        floatx4 t = acc[fi][fj];
        t = __builtin_amdgcn_mfma_f32_16x16x32_bf16(aH[fi], bl, t, 0, 0, 0);
        t = __builtin_amdgcn_mfma_f32_16x16x32_bf16(aL[fi], bh, t, 0, 0, 0);
        t = __builtin_amdgcn_mfma_f32_16x16x32_bf16(aH[fi], bh, t, 0, 0, 0);
        acc[fi][fj] = t;
      }
    }
  }

  float bcol[8];
#pragma unroll
  for (int fj = 0; fj < 8; ++fj)
    bcol[fj] = BIAS ? bias[wn * 128 + fj * 16 + l15] : 0.f;

#pragma unroll
  for (int fi = 0; fi < 4; ++fi) {
    int rb = bm + wm * 64 + fi * 16 + quad * 4;
#pragma unroll
    for (int r = 0; r < 4; ++r) {
      int row = rb + r;
      if (row < M) {
        size_t base = (size_t)row * HDIM + wn * 128 + l15;
        if (SPLIT_OUT) {
#pragma unroll
          for (int fj = 0; fj < 8; ++fj) {
            float v = acc[fi][fj][r] + bcol[fj];
            if (RELU) v = fmaxf(v, 0.f);
            unsigned short h, lo;
            split_f32(v, h, lo);
            CH[base + fj * 16] = h;
            CL[base + fj * 16] = lo;
          }
        } else {
#pragma unroll
          for (int fj = 0; fj < 8; ++fj) {
            float v = acc[fi][fj][r] + bcol[fj];
            if (RELU) v = fmaxf(v, 0.f);
            C[base + fj * 16] = v;
          }
        }
      }
    }
  }
}

// ---------------- GCN aggregation: fp32 t gather (1KB rows), depth-2 prefetch, plane output ----------------

__global__ __launch_bounds__(256)
void aggregate2_kernel(const float* __restrict__ t, const float* __restrict__ dinv,
                       const int* __restrict__ rowptr, const int* __restrict__ col,
                       const float* __restrict__ bias,
                       unsigned short* __restrict__ OH, unsigned short* __restrict__ OL, int n) {
  int gw = (int)((blockIdx.x * 256 + threadIdx.x) >> 6);
  int lane = threadIdx.x & 63;
  if (gw >= n) return;
  float di = dinv[gw];
  float4 v = ((const float4*)(t + (size_t)gw * HDIM))[lane];
  float ss = di * di;
  float a0 = v.x * ss, a1 = v.y * ss, a2 = v.z * ss, a3 = v.w * ss;
  int e0 = rowptr[gw], e1 = rowptr[gw + 1];
  int cnt = e1 - e0;

  float4 cur = make_float4(0.f, 0.f, 0.f, 0.f), nxt = cur;
  float cw = 0.f, nw = 0.f;
  if (cnt > 0) {
    int s = col[e0];
    cw = dinv[s] * di;
    cur = ((const float4*)(t + (size_t)s * HDIM))[lane];
  }
  if (cnt > 1) {
    int s = col[e0 + 1];
    nw = dinv[s] * di;
    nxt = ((const float4*)(t + (size_t)s * HDIM))[lane];
  }
  for (int i = 0; i < cnt; ++i) {
    float4 c = cur;
    float wgt = cw;
    cur = nxt;
    cw = nw;
    if (i + 2 < cnt) {
      int s = col[e0 + i + 2];
      nw = dinv[s] * di;
      nxt = ((const float4*)(t + (size_t)s * HDIM))[lane];
    }
    a0 = fmaf(c.x, wgt, a0);
    a1 = fmaf(c.y, wgt, a1);
    a2 = fmaf(c.z, wgt, a2);
    a3 = fmaf(c.w, wgt, a3);
  }

  float4 bb = ((const float4*)bias)[lane];
  float r0 = fmaxf(a0 + bb.x, 0.f);
  float r1 = fmaxf(a1 + bb.y, 0.f);
  float r2 = fmaxf(a2 + bb.z, 0.f);
  float r3 = fmaxf(a3 + bb.w, 0.f);
  unsigned short h0, h1, h2, h3, l0, l1, l2, l3;
  split_f32(r0, h0, l0);
  split_f32(r1, h1, l1);
  split_f32(r2, h2, l2);
  split_f32(r3, h3, l3);
  ((ushortx4*)(OH + (size_t)gw * HDIM))[lane] = (ushortx4){h0, h1, h2, h3};
  ((ushortx4*)(OL + (size_t)gw * HDIM))[lane] = (ushortx4){l0, l1, l2, l3};
}

// ---------------- row softmax, one wave per row, in-place safe ----------------

__global__ __launch_bounds__(256)
void softmax_kernel(const float* __restrict__ logits, float* __restrict__ outp, int n) {
  int gw = (int)((blockIdx.x * 256 + threadIdx.x) >> 6);
  int lane = threadIdx.x & 63;
  if (gw >= n) return;
  float4 v = ((const float4*)(logits + (size_t)gw * HDIM))[lane];
  float m = fmaxf(fmaxf(v.x, v.y), fmaxf(v.z, v.w));
#pragma unroll
  for (int off = 1; off < 64; off <<= 1) m = fmaxf(m, __shfl_xor(m, off));
  float ex = expf(v.x - m), ey = expf(v.y - m), ez = expf(v.z - m), ew = expf(v.w - m);
  float s = ex + ey + ez + ew;
#pragma unroll
  for (int off = 1; off < 64; off <<= 1) s += __shfl_xor(s, off);
  float inv = 1.0f / s;
  ((float4*)(outp + (size_t)gw * HDIM))[lane] = make_float4(ex * inv, ey * inv, ez * inv, ew * inv);
}

// ---------------- launch ----------------

extern "C" void kernel_launch(void* const* d_in, const int* in_sizes, int n_in,
                              void* d_out, int out_size, void* d_ws, size_t ws_size,
                              hipStream_t stream) {
  const float* x   = (const float*)d_in[0];
  const int*   ei  = (const int*)d_in[1];
  const float* W1  = (const float*)d_in[2];
  const float* b1  = (const float*)d_in[3];
  const float* Wg1 = (const float*)d_in[4];
  const float* bg1 = (const float*)d_in[5];
  const float* Wg2 = (const float*)d_in[6];
  const float* bg2 = (const float*)d_in[7];
  const float* W2  = (const float*)d_in[8];
  const float* b2  = (const float*)d_in[9];
  const float* W3  = (const float*)d_in[10];
  const float* b3  = (const float*)d_in[11];
  float* out = (float*)d_out;

  const int K1 = in_sizes[2] / HDIM;  // 128
  const int N  = in_sizes[0] / K1;    // 50000
  const int E  = in_sizes[1] / 2;     // 300000

  char* w = (char*)d_ws;
  auto alloc = [&](size_t bytes) -> char* {
    char* p = w;
    w += (bytes + 255) & ~(size_t)255;
    return p;
  };
  // activation planes (hi/lo bf16), ping buffer; d_out doubles as fp32 t scratch
  unsigned short* PH = (unsigned short*)alloc((size_t)N * HDIM * 2);
  unsigned short* PL = (unsigned short*)alloc((size_t)N * HDIM * 2);
  float* dinv   = (float*)alloc((size_t)N * sizeof(float));
  int*   deg    = (int*)alloc((size_t)N * sizeof(int));
  int*   rowptr = (int*)alloc((size_t)(N + 1) * sizeof(int));
  int*   cursor = (int*)alloc((size_t)N * sizeof(int));
  int*   col    = (int*)alloc((size_t)E * sizeof(int));
  const int nb  = (N + 255) / 256;
  int*   bsum   = (int*)alloc((size_t)nb * sizeof(int));
  int*   boff   = (int*)alloc((size_t)nb * sizeof(int));
  unsigned short* W1tH  = (unsigned short*)alloc((size_t)HDIM * K1 * 2);
  unsigned short* W1tL  = (unsigned short*)alloc((size_t)HDIM * K1 * 2);
  unsigned short* Wg1tH = (unsigned short*)alloc((size_t)HDIM * HDIM * 2);
  unsigned short* Wg1tL = (unsigned short*)alloc((size_t)HDIM * HDIM * 2);
  unsigned short* Wg2tH = (unsigned short*)alloc((size_t)HDIM * HDIM * 2);
  unsigned short* Wg2tL = (unsigned short*)alloc((size_t)HDIM * HDIM * 2);
  unsigned short* W2tH  = (unsigned short*)alloc((size_t)HDIM * HDIM * 2);
  unsigned short* W2tL  = (unsigned short*)alloc((size_t)HDIM * HDIM * 2);
  unsigned short* W3tH  = (unsigned short*)alloc((size_t)HDIM * HDIM * 2);
  unsigned short* W3tL  = (unsigned short*)alloc((size_t)HDIM * HDIM * 2);

  const int ge = (E + 255) / 256;
  const int gn = (N + 255) / 256;
  const int kshift1 = (K1 == 128) ? 7 : 8;

  prep_w_kernel<<<(HDIM * K1 + 255) / 256, 256, 0, stream>>>(W1, W1tH, W1tL, kshift1);
  prep_w_kernel<<<(HDIM * HDIM + 255) / 256, 256, 0, stream>>>(Wg1, Wg1tH, Wg1tL, 8);
  prep_w_kernel<<<(HDIM * HDIM + 255) / 256, 256, 0, stream>>>(Wg2, Wg2tH, Wg2tL, 8);
  prep_w_kernel<<<(HDIM * HDIM + 255) / 256, 256, 0, stream>>>(W2, W2tH, W2tL, 8);
  prep_w_kernel<<<(HDIM * HDIM + 255) / 256, 256, 0, stream>>>(W3, W3tH, W3tL, 8);

  hipMemsetAsync(deg, 0, (size_t)N * sizeof(int), stream);
  deg_count_kernel<<<ge, 256, 0, stream>>>(ei, deg, E);
  dinv_kernel<<<gn, 256, 0, stream>>>(deg, dinv, N);
  block_sum_kernel<<<nb, 256, 0, stream>>>(deg, bsum, N);
  scan_bsums_kernel<<<1, 256, 0, stream>>>(bsum, boff, rowptr, nb, N);
  scan_final_kernel<<<nb, 256, 0, stream>>>(deg, boff, rowptr, cursor, N);
  fill_csr_kernel<<<ge, 256, 0, stream>>>(ei, cursor, col, E);

  dim3 g1grid(HDIM / 128, (N + 127) / 128);
  const int g2grid = (N + 127) / 128;
  const int gagg = (N + 3) / 4;

  // h0 = relu(x@W1+b1) -> planes P
  mfma_gemm_splitA<true, true><<<g1grid, 256, 0, stream>>>(x, W1tH, W1tL, b1, PH, PL, N, K1);
  // t1 = h0@Wg1 -> out (fp32 scratch)
  mfma_gemm2<false, false, false><<<g2grid, 256, 0, stream>>>(PH, PL, Wg1tH, Wg1tL, nullptr, out, nullptr, nullptr, N);
  // h1 = relu(agg(t1)+bg1) -> planes P
  aggregate2_kernel<<<gagg, 256, 0, stream>>>(out, dinv, rowptr, col, bg1, PH, PL, N);
  // t2 = h1@Wg2 -> out
  mfma_gemm2<false, false, false><<<g2grid, 256, 0, stream>>>(PH, PL, Wg2tH, Wg2tL, nullptr, out, nullptr, nullptr, N);
  // h2 = relu(agg(t2)+bg2) -> planes P
  aggregate2_kernel<<<gagg, 256, 0, stream>>>(out, dinv, rowptr, col, bg2, PH, PL, N);
  // h3 = relu(h2@W2+b2) -> planes P (in-place: each block reads/writes only its own 128 rows)
  mfma_gemm2<true, true, true><<<g2grid, 256, 0, stream>>>(PH, PL, W2tH, W2tL, b2, nullptr, PH, PL, N);
  // logits = h3@W3+b3 -> out
  mfma_gemm2<true, false, false><<<g2grid, 256, 0, stream>>>(PH, PL, W3tH, W3tL, b3, out, nullptr, nullptr, N);
  // softmax in place
  softmax_kernel<<<gagg, 256, 0, stream>>>(out, out, N);
}